// Round 13
// baseline (99.284 us; speedup 1.0000x reference)
//
#include <hip/hip_runtime.h>
#include <stdint.h>

typedef float f32x4 __attribute__((ext_vector_type(4)));
typedef __bf16 bf16x8 __attribute__((ext_vector_type(8)));
typedef __bf16 bf16x4 __attribute__((ext_vector_type(4)));

#define NROWS 65536     // 16 * 4096 x-rows
#define NCODES 4096
#define NDIM 64
#define STEPS 128       // 4096 codes / 32 codes per step (full sweep per block)
#define SSTEP 2         // steps per barrier phase
#define PHASES (STEPS / SSTEP)  // 64
#define BIAS 2048.0f    // all T' = dot - c^2/2 - BIAS are < 0 (|dot| <= ~120)
#define CBMASK 0x7FFFF  // wrap within the 512KB codebook (rotation)

// ws layout (bytes):
//   [0x000000, 0x080000): codes bf16        4096*64*2 = 512 KB
//   [0x080000, 0x084000): nc2p paired (-||c||^2/2 - BIAS): float2[2048]
//       pair index = step*16 + col (step=code>>5) ; .x = col, .y = col+16

__device__ __forceinline__ void gld_lds16(const void* g, void* l) {
  __builtin_amdgcn_global_load_lds(
      (const __attribute__((address_space(1))) unsigned int*)g,
      (__attribute__((address_space(3))) unsigned int*)l, 16, 0, 0);
}

__device__ __forceinline__ uint32_t umin2(uint32_t a, uint32_t b) {
  return a < b ? a : b;
}

// Coalesced prep: 65536 threads, one f32x4 each; 16 lanes per code row.
// Writes bf16 codebook + paired (-||c||^2/2 - BIAS) layout (see ws map).
__global__ __launch_bounds__(256) void prep_codes_k(const float* __restrict__ codes,
                                                    float* __restrict__ nc2p,
                                                    __bf16* __restrict__ cb) {
  const int t = blockIdx.x * 256 + threadIdx.x;  // 0..65535
  f32x4 v = *(const f32x4*)(codes + t * 4);
  bf16x4 o;
  float s = 0.f;
#pragma unroll
  for (int j = 0; j < 4; j++) {
    o[j] = (__bf16)v[j];
    s += v[j] * v[j];
  }
  *(bf16x4*)(cb + t * 4) = o;
  s += __shfl_xor(s, 1);
  s += __shfl_xor(s, 2);
  s += __shfl_xor(s, 4);
  s += __shfl_xor(s, 8);
  if ((threadIdx.x & 15) == 0) {
    const int c = t >> 4;  // code id 0..4095
    const int pidx = (c >> 5) * 16 + (c & 15);  // step*16 + col
    const int half = (c >> 4) & 1;
    nc2p[pidx * 2 + half] = -0.5f * s - BIAS;
  }
}

// NSPLIT=1 ROUND: 512 blocks x 128 rows; each block sweeps ALL 4096 codes
// (128 steps of 32, 64 dbuf phases) -> A-fragments loaded ONCE per row
// (was 4x), no karr/x2arr traffic, no nn_final kernel. out[] written
// directly in the epilogue. Code id = 12 low bits of the u32 key
// (mask 0xFFFFF000; trunc error <=1.0 on T vs ~70 margin on threshold).
// Phase rotation s0=bid&127 spreads the 512 blocks across the codebook
// (L2-resident per XCD after first sweep). u32-key argmax (r11): C-init
// = -c^2/2-2048 < 0 -> unsigned bit order = descending float order;
// key=(bits&~4095)|code; umin==argmax, lowest-code tie-break; merge via
// v_min3_u32. Swizzle involution (rule #21): LDS[P]=G[P^((P>>7&7)<<4)]
// store side, reader XORs the same. A-frag: lane holds
// A[m=lane&15][k=quad*8+j]. C/D: col(n)=lane&15, row(m)=quad*4+reg.
__global__ __launch_bounds__(256, 6) void nn_main(const float* __restrict__ x,
                                                  const __bf16* __restrict__ cbv,
                                                  const float2* __restrict__ nc2p,
                                                  int* __restrict__ out) {
  const int tid  = threadIdx.x;
  const int lane = tid & 63;
  const int w    = tid >> 6;   // wave id = row chunk
  const int col  = lane & 15;
  const int quad = lane >> 4;
  const int bid  = blockIdx.x;             // 0..511
  const int rowbase = bid * 128 + w * 32;
  const int s0 = bid & 127;                // phase-rotation start step
  const char* cbb = (const char*)cbv;

  __shared__ __align__(16) char stage[2][SSTEP * 4096];  // 16 KB
  __shared__ __align__(8) float2 ncl[2048];              // 16 KB: [step][col]

  // ---- stage all nc2 pairs (16 KB) + rotated phase 0 (8 KB) ----
  const uint32_t schunk = ((uint32_t)(tid * 16)) ^ ((((uint32_t)tid >> 3) & 7u) << 4);
  const char* srcbase = cbb + schunk;
  const uint32_t rot = (uint32_t)s0 * 4096u;
#pragma unroll
  for (int i = 0; i < 4; i++)
    gld_lds16((const char*)nc2p + i * 4096 + tid * 16,
              (char*)ncl + i * 4096 + w * 1024);
#pragma unroll
  for (int i = 0; i < SSTEP; i++)
    gld_lds16(srcbase + ((rot + i * 4096u) & CBMASK),
              &stage[0][i * 4096 + w * 1024]);

  // ---- A fragments (fp32 -> bf16) + ||x||^2 (overlaps with stages) ----
  bf16x8 a[2][2];
  float x2part[2];
#pragma unroll
  for (int rt = 0; rt < 2; rt++) {
    const float* xr = x + (rowbase + rt * 16 + col) * NDIM + quad * 8;
    float p = 0.f;
#pragma unroll
    for (int kc = 0; kc < 2; kc++) {
      f32x4 v0 = *(const f32x4*)(xr + kc * 32);
      f32x4 v1 = *(const f32x4*)(xr + kc * 32 + 4);
      bf16x8 af;
#pragma unroll
      for (int j = 0; j < 4; j++) {
        af[j]     = (__bf16)v0[j];
        af[j + 4] = (__bf16)v1[j];
        p += v0[j] * v0[j] + v1[j] * v1[j];
      }
      a[rt][kc] = af;
    }
    x2part[rt] = p;
  }
#pragma unroll
  for (int rt = 0; rt < 2; rt++) {
    float p = x2part[rt];
    p += __shfl_xor(p, 16);
    p += __shfl_xor(p, 32);
    x2part[rt] = p;  // every lane: x2 of row rt*16 + col
  }

  uint32_t bestK[2][4];
#pragma unroll
  for (int rt = 0; rt < 2; rt++)
#pragma unroll
    for (int j = 0; j < 4; j++) bestK[rt][j] = 0xFFFFFFFFu;

  // ---- reader LDS byte offsets (swizzled), within a 4KB tile ----
  const uint32_t swz = ((uint32_t)(col & 7)) << 4;
  const uint32_t o00 = ((uint32_t)(col * 128 + quad * 16)) ^ swz;
  const uint32_t o01 = ((uint32_t)(col * 128 + 64 + quad * 16)) ^ swz;
  const uint32_t o10 = ((uint32_t)(2048 + col * 128 + quad * 16)) ^ swz;
  const uint32_t o11 = ((uint32_t)(2048 + col * 128 + 64 + quad * 16)) ^ swz;

  __syncthreads();  // ncl + phase 0 staged

#pragma unroll 1
  for (int p = 0; p < PHASES; ++p) {
    // prefetch next phase into the other buffer (wrapped rotated offsets)
    if (p < PHASES - 1) {
      const uint32_t pb = rot + (uint32_t)(p + 1) * (SSTEP * 4096u);
      char* dst = &stage[(p + 1) & 1][w * 1024];
#pragma unroll
      for (int i = 0; i < SSTEP; i++)
        gld_lds16(srcbase + ((pb + i * 4096u) & CBMASK), dst + i * 4096);
    }
    const char* sb = stage[p & 1];
#pragma unroll
    for (int ss = 0; ss < SSTEP; ss++) {
      const int s_eff = (s0 + p * SSTEP + ss) & 127;  // rotated step 0..127
      const float2 nv = ncl[s_eff * 16 + col];
      bf16x8 b00 = *(const bf16x8*)(sb + ss * 4096 + o00);
      bf16x8 b01 = *(const bf16x8*)(sb + ss * 4096 + o01);
      bf16x8 b10 = *(const bf16x8*)(sb + ss * 4096 + o10);
      bf16x8 b11 = *(const bf16x8*)(sb + ss * 4096 + o11);
      f32x4 ci0 = {nv.x, nv.x, nv.x, nv.x};
      f32x4 ci1 = {nv.y, nv.y, nv.y, nv.y};
      // code-id payloads (low 12 bits of key); s_eff<<5 uniform -> SALU
      const uint32_t vk0 = (uint32_t)(col | (s_eff << 5));
      const uint32_t vk1 = vk0 | 16u;
#pragma unroll
      for (int rt = 0; rt < 2; rt++) {
        f32x4 acc0 = __builtin_amdgcn_mfma_f32_16x16x32_bf16(a[rt][0], b00, ci0, 0, 0, 0);
        acc0 = __builtin_amdgcn_mfma_f32_16x16x32_bf16(a[rt][1], b01, acc0, 0, 0, 0);
        f32x4 acc1 = __builtin_amdgcn_mfma_f32_16x16x32_bf16(a[rt][0], b10, ci1, 0, 0, 0);
        acc1 = __builtin_amdgcn_mfma_f32_16x16x32_bf16(a[rt][1], b11, acc1, 0, 0, 0);
#pragma unroll
        for (int j = 0; j < 4; j++) {
          const uint32_t k0 = (__builtin_bit_cast(uint32_t, acc0[j]) & 0xFFFFF000u) | vk0;
          const uint32_t k1 = (__builtin_bit_cast(uint32_t, acc1[j]) & 0xFFFFF000u) | vk1;
          bestK[rt][j] = umin2(bestK[rt][j], umin2(k0, k1));  // v_min3_u32
        }
      }
    }
    __syncthreads();  // next buffer staged; this buffer free
  }

  // ---- epilogue: butterfly umin over 16 lanes, threshold, store out[] ----
#pragma unroll
  for (int rt = 0; rt < 2; rt++) {
#pragma unroll
    for (int j = 0; j < 4; j++) {
      uint32_t bk = bestK[rt][j];
#pragma unroll
      for (int off = 1; off < 16; off <<= 1) {
        const uint32_t ok = (uint32_t)__shfl_xor((int)bk, off);
        bk = umin2(bk, ok);
      }
      // x2 of row rt*16 + quad*4 + j lives in same-quad lane with col=quad*4+j
      const float x2v = __shfl(x2part[rt], (lane & 48) + quad * 4 + j);
      if (col == 0) {
        const float Tp = __builtin_bit_cast(float, bk & 0xFFFFF000u);  // T - BIAS
        const float d2 = fmaf(-2.0f, Tp, x2v) - 2.0f * BIAS;           // x2 - 2T
        out[rowbase + rt * 16 + quad * 4 + j] =
            (d2 <= 0.1f) ? (int)(bk & 4095u) : -1;
      }
    }
  }
}

extern "C" void kernel_launch(void* const* d_in, const int* in_sizes, int n_in,
                              void* d_out, int out_size, void* d_ws, size_t ws_size,
                              hipStream_t stream) {
  const float* x = (const float*)d_in[0];      // [65536][64] fp32
  const float* codes = (const float*)d_in[1];  // [4096][64] fp32
  int* out = (int*)d_out;                      // [65536] int32

  char* ws = (char*)d_ws;
  __bf16* cb = (__bf16*)ws;                     // 512 KB
  float* nc2p = (float*)(ws + 0x080000);        // 16 KB (float2[2048])

  prep_codes_k<<<256, 256, 0, stream>>>(codes, nc2p, cb);
  nn_main<<<512, 256, 0, stream>>>(x, cb, (const float2*)nc2p, out);
}